// Round 1
// baseline (350.045 us; speedup 1.0000x reference)
//
#include <hip/hip_runtime.h>

// Multi-head causal attention: B=256 T=256 D=384 H=6 HS=64
// x[B,T,D] f32, W_qkv[H,D,192] f32, W_out[384,384] f32, b_out[384] f32
// out[B,T,D] f32.
// Pipeline: prep (W transpose->bf16, fold 0.125 into Wq) -> qkv GEMM (bf16 MFMA)
//   -> flash attention (S^T trick, online softmax) -> out GEMM + bias.

typedef __attribute__((ext_vector_type(8))) short short8;
typedef __attribute__((ext_vector_type(4))) float f32x4;

#define NBATCH 256
#define NT 256
#define ND 384
#define NH 6
#define NHS 64
#define BT 65536   // NBATCH*NT

__device__ __forceinline__ unsigned short f2bf(float f) {
  unsigned int u = __float_as_uint(f);
  u += 0x7fffu + ((u >> 16) & 1u);
  return (unsigned short)(u >> 16);
}

__device__ __forceinline__ ushort4 pack4(f32x4 v) {
  ushort4 p;
  p.x = f2bf(v[0]); p.y = f2bf(v[1]); p.z = f2bf(v[2]); p.w = f2bf(v[3]);
  return p;
}

// ---------------- prep: W_qkv [H][D][192] f32 -> Wt [H][192][D] bf16 (Q rows *0.125)
__global__ __launch_bounds__(256) void prep_wqkv(const float* __restrict__ W,
                                                 unsigned short* __restrict__ Wt) {
  int idx = blockIdx.x * 256 + threadIdx.x;        // total NH*192*ND = 442368
  int h = idx / (192 * ND);
  int rem = idx % (192 * ND);
  int e = rem / ND;
  int d = rem % ND;
  float v = W[((size_t)h * ND + d) * 192 + e];
  if (e < 64) v *= 0.125f;                          // fold 1/sqrt(HS) into Q
  Wt[idx] = f2bf(v);
}

// ---------------- prep: W_out [384][384] f32 -> Wot [n=384][k=384] bf16 (transposed)
__global__ __launch_bounds__(256) void prep_wout(const float* __restrict__ W,
                                                 unsigned short* __restrict__ Wt) {
  int idx = blockIdx.x * 256 + threadIdx.x;        // total 147456
  int n = idx / ND;
  int k = idx % ND;
  Wt[idx] = f2bf(W[(size_t)k * ND + n]);
}

// ---------------- QKV projection GEMM
// C[m][n] = sum_k x[m][k] * W[k][n], per (head h, part p). Tile 128x64, K-step 32.
// p=0 -> Q[b,h,t,e] bf16 (pre-scaled); p=1 -> K[b,h,t,e]; p=2 -> Vt[b,h,e,t].
__global__ __launch_bounds__(256) void qkv_gemm(const float* __restrict__ x,
                                                const unsigned short* __restrict__ Wt,
                                                unsigned short* __restrict__ Qb,
                                                unsigned short* __restrict__ Kb,
                                                unsigned short* __restrict__ Vtb) {
  __shared__ __align__(16) unsigned short As[128 * 48];  // stride 48 (16B-aligned rows, spread banks)
  __shared__ __align__(16) unsigned short Bs[64 * 48];
  const int tid = threadIdx.x;
  const int lane = tid & 63, w = tid >> 6;
  const int l15 = lane & 15, lg = lane >> 4;
  const int wm = w >> 1, wn = w & 1;
  const int hp = blockIdx.x;                  // 0..17 (head*3+part) -- inner for L2 reuse of x
  const int m0 = blockIdx.y * 128;
  const int h = hp / 3, p = hp % 3;
  const unsigned short* Wb = Wt + (size_t)(h * 192 + p * 64) * ND;

  f32x4 acc[4][2];
#pragma unroll
  for (int i = 0; i < 4; i++)
#pragma unroll
    for (int j = 0; j < 2; j++) acc[i][j] = (f32x4){0.f, 0.f, 0.f, 0.f};

  const int arow = tid >> 3, acol = (tid & 7) * 4;   // A: 128x32 f32, 4 float4/thread
  const int brow = tid >> 2, bk = (tid & 3) * 8;     // B: 64x32 bf16, 1 short8/thread

  for (int kt = 0; kt < 12; ++kt) {
    const int k0 = kt * 32;
    float4 av[4];
#pragma unroll
    for (int i = 0; i < 4; i++)
      av[i] = *reinterpret_cast<const float4*>(&x[(size_t)(m0 + i * 32 + arow) * ND + k0 + acol]);
    short8 bv = *reinterpret_cast<const short8*>(&Wb[(size_t)brow * ND + k0 + bk]);
    __syncthreads();
#pragma unroll
    for (int i = 0; i < 4; i++) {
      ushort4 pk;
      pk.x = f2bf(av[i].x); pk.y = f2bf(av[i].y); pk.z = f2bf(av[i].z); pk.w = f2bf(av[i].w);
      *reinterpret_cast<ushort4*>(&As[(i * 32 + arow) * 48 + acol]) = pk;
    }
    *reinterpret_cast<short8*>(&Bs[brow * 48 + bk]) = bv;
    __syncthreads();
    short8 af[4], bf[2];
#pragma unroll
    for (int mi = 0; mi < 4; mi++)
      af[mi] = *reinterpret_cast<const short8*>(&As[(wm * 64 + mi * 16 + l15) * 48 + lg * 8]);
#pragma unroll
    for (int ni = 0; ni < 2; ni++)
      bf[ni] = *reinterpret_cast<const short8*>(&Bs[(wn * 32 + ni * 16 + l15) * 48 + lg * 8]);
#pragma unroll
    for (int mi = 0; mi < 4; mi++)
#pragma unroll
      for (int ni = 0; ni < 2; ni++)
        acc[mi][ni] = __builtin_amdgcn_mfma_f32_16x16x32_bf16(af[mi], bf[ni], acc[mi][ni], 0, 0, 0);
  }

  // epilogue: D layout row=(lane>>4)*4+r, col=lane&15  [verified m89/m91]
  const int b = m0 >> 8, t0 = m0 & 255;
  const size_t bh = (size_t)b * NH + h;
#pragma unroll
  for (int mi = 0; mi < 4; mi++)
#pragma unroll
    for (int ni = 0; ni < 2; ni++) {
      const int c = wn * 32 + ni * 16 + l15;       // e within 64
      const int mr = wm * 64 + mi * 16 + lg * 4;   // t within tile
      if (p == 2) {
        *reinterpret_cast<ushort4*>(&Vtb[(bh * 64 + c) * NT + t0 + mr]) = pack4(acc[mi][ni]);
      } else {
        unsigned short* dst = (p == 0) ? Qb : Kb;
        size_t base = (bh * NT + t0 + mr) * 64 + c;
#pragma unroll
        for (int r = 0; r < 4; r++) dst[base + (size_t)r * 64] = f2bf(acc[mi][ni][r]);
      }
    }
}

// ---------------- attention: one block per (b,h); 4 waves x 64 q-rows; kv tiles of 64
__global__ __launch_bounds__(256) void attn_fwd(const unsigned short* __restrict__ Qb,
                                                const unsigned short* __restrict__ Kb,
                                                const unsigned short* __restrict__ Vtb,
                                                unsigned short* __restrict__ AO) {
  __shared__ __align__(16) unsigned short Plds[4][64 * 64];  // wave-private P buffer (XOR-swizzled)
  const int bh = blockIdx.x;
  const int tid = threadIdx.x;
  const int w = tid >> 6, lane = tid & 63;
  const int l15 = lane & 15, lg = lane >> 4;
  const int q0 = w * 64;
  const unsigned short* Qh = Qb + (size_t)bh * NT * 64;
  const unsigned short* Kh = Kb + (size_t)bh * NT * 64;
  const unsigned short* Vh = Vtb + (size_t)bh * 64 * NT;
  unsigned short* P = Plds[w];
  const int swz = (l15 & 7) << 3;

  // Q fragments (Q pre-scaled by 1/8): B-operand of mfma(K,Q)
  short8 qf[4][2];
#pragma unroll
  for (int mi = 0; mi < 4; mi++)
#pragma unroll
    for (int kb = 0; kb < 2; kb++)
      qf[mi][kb] = *reinterpret_cast<const short8*>(
          &Qh[(size_t)(q0 + mi * 16 + l15) * 64 + kb * 32 + lg * 8]);

  f32x4 ot[4][4];  // O^T accumulator: [e-block][q-block]
#pragma unroll
  for (int i = 0; i < 4; i++)
#pragma unroll
    for (int j = 0; j < 4; j++) ot[i][j] = (f32x4){0.f, 0.f, 0.f, 0.f};
  float mprev[4], lsum[4];
#pragma unroll
  for (int mi = 0; mi < 4; mi++) { mprev[mi] = -1e30f; lsum[mi] = 0.f; }

  for (int tile = 0; tile <= w; ++tile) {
    const int kv0 = tile * 64;
    short8 kf[4][2];
#pragma unroll
    for (int ni = 0; ni < 4; ni++)
#pragma unroll
      for (int kb = 0; kb < 2; kb++)
        kf[ni][kb] = *reinterpret_cast<const short8*>(
            &Kh[(size_t)(kv0 + ni * 16 + l15) * 64 + kb * 32 + lg * 8]);

    // S^T[kv][q] = K . Q^T  (lane holds kv=(lg*4+r)+16*ni rows of column q=l15+16*mi)
    f32x4 st[4][4];
#pragma unroll
    for (int i = 0; i < 4; i++)
#pragma unroll
      for (int j = 0; j < 4; j++) st[i][j] = (f32x4){0.f, 0.f, 0.f, 0.f};
#pragma unroll
    for (int ni = 0; ni < 4; ni++)
#pragma unroll
      for (int mi = 0; mi < 4; mi++)
#pragma unroll
        for (int kb = 0; kb < 2; kb++)
          st[ni][mi] = __builtin_amdgcn_mfma_f32_16x16x32_bf16(kf[ni][kb], qf[mi][kb], st[ni][mi], 0, 0, 0);

    if (tile == w) {  // causal mask on diagonal tile
#pragma unroll
      for (int ni = 0; ni < 4; ni++)
#pragma unroll
        for (int mi = 0; mi < 4; mi++)
#pragma unroll
          for (int r = 0; r < 4; r++)
            if (kv0 + ni * 16 + lg * 4 + r > q0 + mi * 16 + l15) st[ni][mi][r] = -1e30f;
    }

    // online softmax per q-column block mi (kv-reduce: 16 regs local + shfl_xor 16/32)
#pragma unroll
    for (int mi = 0; mi < 4; mi++) {
      float mp = -1e30f;
#pragma unroll
      for (int ni = 0; ni < 4; ni++)
#pragma unroll
        for (int r = 0; r < 4; r++) mp = fmaxf(mp, st[ni][mi][r]);
      mp = fmaxf(mp, __shfl_xor(mp, 16));
      mp = fmaxf(mp, __shfl_xor(mp, 32));
      const float mnew = fmaxf(mprev[mi], mp);
      const float corr = __expf(mprev[mi] - mnew);
      mprev[mi] = mnew;
      float ls = 0.f;
#pragma unroll
      for (int ni = 0; ni < 4; ni++)
#pragma unroll
        for (int r = 0; r < 4; r++) {
          float pv = __expf(st[ni][mi][r] - mnew);
          st[ni][mi][r] = pv;
          ls += pv;
        }
      ls += __shfl_xor(ls, 16);
      ls += __shfl_xor(ls, 32);
      lsum[mi] = lsum[mi] * corr + ls;
#pragma unroll
      for (int erb = 0; erb < 4; erb++)
#pragma unroll
        for (int r = 0; r < 4; r++) ot[erb][mi][r] *= corr;
      // stash P as P[q][kv] bf16 in LDS (XOR swizzle keyed on q&7 -> conflict-light)
      const int qloc = mi * 16 + l15;
#pragma unroll
      for (int ni = 0; ni < 4; ni++)
        *reinterpret_cast<ushort4*>(&P[qloc * 64 + ((ni * 16 + lg * 4) ^ swz)]) = pack4(st[ni][mi]);
    }

    // PV: O^T[e][q] += V^T[e][kv] * P^T[kv][q]
    short8 va[4][2], pb[2][4];
#pragma unroll
    for (int erb = 0; erb < 4; erb++)
#pragma unroll
      for (int kk = 0; kk < 2; kk++)
        va[erb][kk] = *reinterpret_cast<const short8*>(
            &Vh[(size_t)(erb * 16 + l15) * NT + kv0 + kk * 32 + lg * 8]);
#pragma unroll
    for (int kk = 0; kk < 2; kk++)
#pragma unroll
      for (int mi = 0; mi < 4; mi++)
        pb[kk][mi] = *reinterpret_cast<const short8*>(
            &P[(mi * 16 + l15) * 64 + ((kk * 32 + lg * 8) ^ swz)]);
#pragma unroll
    for (int erb = 0; erb < 4; erb++)
#pragma unroll
      for (int mi = 0; mi < 4; mi++)
#pragma unroll
        for (int kk = 0; kk < 2; kk++)
          ot[erb][mi] = __builtin_amdgcn_mfma_f32_16x16x32_bf16(va[erb][kk], pb[kk][mi], ot[erb][mi], 0, 0, 0);
  }

  // epilogue: AO[b*T+q][h*64+e] bf16
  const int b = bh / NH, h = bh % NH;
#pragma unroll
  for (int mi = 0; mi < 4; mi++) {
    const float rl = 1.0f / lsum[mi];
    const int q = q0 + mi * 16 + l15;
#pragma unroll
    for (int erb = 0; erb < 4; erb++) {
      f32x4 v;
#pragma unroll
      for (int r = 0; r < 4; r++) v[r] = ot[erb][mi][r] * rl;
      *reinterpret_cast<ushort4*>(&AO[((size_t)(b * NT + q)) * ND + h * 64 + erb * 16 + lg * 4]) =
          pack4(v);
    }
  }
}

// ---------------- output projection: out[m][n] = AO[m][k] * W_out[k][n] + b_out[n]
__global__ __launch_bounds__(256) void out_gemm(const unsigned short* __restrict__ AO,
                                                const unsigned short* __restrict__ Wot,
                                                const float* __restrict__ bout,
                                                float* __restrict__ out) {
  __shared__ __align__(16) unsigned short As[128 * 48];
  __shared__ __align__(16) unsigned short Bs[64 * 48];
  const int tid = threadIdx.x;
  const int lane = tid & 63, w = tid >> 6;
  const int l15 = lane & 15, lg = lane >> 4;
  const int wm = w >> 1, wn = w & 1;
  const int n0 = blockIdx.x * 64;   // 6 n-tiles (inner -> L2 reuse of AO tile)
  const int m0 = blockIdx.y * 128;

  f32x4 acc[4][2];
#pragma unroll
  for (int i = 0; i < 4; i++)
#pragma unroll
    for (int j = 0; j < 2; j++) acc[i][j] = (f32x4){0.f, 0.f, 0.f, 0.f};

  const int arow = tid >> 2, ak = (tid & 3) * 8;   // 64 rows per pass, 2 passes

  for (int kt = 0; kt < 12; ++kt) {
    const int k0 = kt * 32;
    short8 av0 = *reinterpret_cast<const short8*>(&AO[(size_t)(m0 + arow) * ND + k0 + ak]);
    short8 av1 = *reinterpret_cast<const short8*>(&AO[(size_t)(m0 + 64 + arow) * ND + k0 + ak]);
    short8 bv = *reinterpret_cast<const short8*>(&Wot[(size_t)(n0 + arow) * ND + k0 + ak]);
    __syncthreads();
    *reinterpret_cast<short8*>(&As[arow * 48 + ak]) = av0;
    *reinterpret_cast<short8*>(&As[(64 + arow) * 48 + ak]) = av1;
    *reinterpret_cast<short8*>(&Bs[arow * 48 + ak]) = bv;
    __syncthreads();
    short8 af[4], bf[2];
#pragma unroll
    for (int mi = 0; mi < 4; mi++)
      af[mi] = *reinterpret_cast<const short8*>(&As[(wm * 64 + mi * 16 + l15) * 48 + lg * 8]);
#pragma unroll
    for (int ni = 0; ni < 2; ni++)
      bf[ni] = *reinterpret_cast<const short8*>(&Bs[(wn * 32 + ni * 16 + l15) * 48 + lg * 8]);
#pragma unroll
    for (int mi = 0; mi < 4; mi++)
#pragma unroll
      for (int ni = 0; ni < 2; ni++)
        acc[mi][ni] = __builtin_amdgcn_mfma_f32_16x16x32_bf16(af[mi], bf[ni], acc[mi][ni], 0, 0, 0);
  }

#pragma unroll
  for (int mi = 0; mi < 4; mi++)
#pragma unroll
    for (int ni = 0; ni < 2; ni++) {
      const int c = n0 + wn * 32 + ni * 16 + l15;
      const int mr = m0 + wm * 64 + mi * 16 + lg * 4;
      const float bb = bout[c];
#pragma unroll
      for (int r = 0; r < 4; r++) out[(size_t)(mr + r) * ND + c] = acc[mi][ni][r] + bb;
    }
}

// ---------------- launcher
extern "C" void kernel_launch(void* const* d_in, const int* in_sizes, int n_in,
                              void* d_out, int out_size, void* d_ws, size_t ws_size,
                              hipStream_t stream) {
  const float* x = (const float*)d_in[0];
  const float* Wqkv = (const float*)d_in[1];
  const float* Wout = (const float*)d_in[2];
  const float* bout = (const float*)d_in[3];

  char* ws = (char*)d_ws;
  const size_t SZ_QKV = (size_t)NBATCH * NH * NT * NHS * 2;  // 50331648 each
  unsigned short* Qb   = (unsigned short*)(ws);
  unsigned short* Kb   = (unsigned short*)(ws + SZ_QKV);
  unsigned short* Vtb  = (unsigned short*)(ws + 2 * SZ_QKV);
  unsigned short* AO   = (unsigned short*)(ws + 3 * SZ_QKV);
  unsigned short* Wqt  = (unsigned short*)(ws + 4 * SZ_QKV);                 // 884736 B
  unsigned short* Wot  = (unsigned short*)(ws + 4 * SZ_QKV + 884736);        // 294912 B

  prep_wqkv<<<1728, 256, 0, stream>>>(Wqkv, Wqt);
  prep_wout<<<576, 256, 0, stream>>>(Wout, Wot);
  qkv_gemm<<<dim3(18, 512), 256, 0, stream>>>(x, Wqt, Qb, Kb, Vtb);
  attn_fwd<<<NBATCH * NH, 256, 0, stream>>>(Qb, Kb, Vtb, AO);
  out_gemm<<<dim3(6, 512), 256, 0, stream>>>(AO, Wot, bout, (float*)d_out);
}

// Round 2
// 263.871 us; speedup vs baseline: 1.3266x; 1.3266x over previous
//
#include <hip/hip_runtime.h>

// Multi-head causal attention: B=256 T=256 D=384 H=6 HS=64
// Pipeline: x->bf16 | W preps | per-head fused QKV GEMM (128x192 tile,
// global_load_lds + XOR swizzle + XCD swizzle, 2-phase prefetch)
// -> flash attention (S^T trick) -> out GEMM + bias.

typedef __attribute__((ext_vector_type(8))) short short8;
typedef __attribute__((ext_vector_type(4))) float f32x4;

#define NBATCH 256
#define NT 256
#define ND 384
#define NH 6
#define NHS 64

__device__ __forceinline__ unsigned short f2bf(float f) {
  unsigned int u = __float_as_uint(f);
  u += 0x7fffu + ((u >> 16) & 1u);
  return (unsigned short)(u >> 16);
}

__device__ __forceinline__ ushort4 pack4(f32x4 v) {
  ushort4 p;
  p.x = f2bf(v[0]); p.y = f2bf(v[1]); p.z = f2bf(v[2]); p.w = f2bf(v[3]);
  return p;
}

__device__ __forceinline__ void gload16(const void* g, void* l) {
  __builtin_amdgcn_global_load_lds(
      (const __attribute__((address_space(1))) void*)g,
      (__attribute__((address_space(3))) void*)l, 16, 0, 0);
}

// ---------------- x [B*T][D] f32 -> bf16
__global__ __launch_bounds__(256) void x_to_bf16(const float* __restrict__ x,
                                                 unsigned short* __restrict__ xb) {
  size_t i = ((size_t)blockIdx.x * 256 + threadIdx.x) * 8;  // 25165824 total
  float4 a = *reinterpret_cast<const float4*>(&x[i]);
  float4 b = *reinterpret_cast<const float4*>(&x[i + 4]);
  ushort4 lo, hi;
  lo.x = f2bf(a.x); lo.y = f2bf(a.y); lo.z = f2bf(a.z); lo.w = f2bf(a.w);
  hi.x = f2bf(b.x); hi.y = f2bf(b.y); hi.z = f2bf(b.z); hi.w = f2bf(b.w);
  *reinterpret_cast<ushort4*>(&xb[i]) = lo;
  *reinterpret_cast<ushort4*>(&xb[i + 4]) = hi;
}

// ---------------- prep: W_qkv [H][D][192] f32 -> Wt [H][192][D] bf16 (Q rows *0.125)
__global__ __launch_bounds__(256) void prep_wqkv(const float* __restrict__ W,
                                                 unsigned short* __restrict__ Wt) {
  int idx = blockIdx.x * 256 + threadIdx.x;        // NH*192*ND = 442368
  int h = idx / (192 * ND);
  int rem = idx % (192 * ND);
  int e = rem / ND;
  int d = rem % ND;
  float v = W[((size_t)h * ND + d) * 192 + e];
  if (e < 64) v *= 0.125f;
  Wt[idx] = f2bf(v);
}

// ---------------- prep: W_out [384][384] f32 -> Wot [n][k] bf16 (transposed)
__global__ __launch_bounds__(256) void prep_wout(const float* __restrict__ W,
                                                 unsigned short* __restrict__ Wt) {
  int idx = blockIdx.x * 256 + threadIdx.x;        // 147456
  int n = idx / ND;
  int k = idx % ND;
  Wt[idx] = f2bf(W[(size_t)k * ND + n]);
}

// ---------------- fused per-head QKV GEMM: C[128 m][192 n] per block
// A = xb[m][k] bf16, B = Wqt[h][n][k] bf16. BK=64, double-buffered LDS via
// global_load_lds (linear dest, pre-swizzled source; reads XOR-deswizzle).
// 4 waves, each owns 64x96. p=0->Q (pre-scaled), p=1->K, p=2->Vt.
__global__ __launch_bounds__(256, 2) void qkv_gemm(const unsigned short* __restrict__ xb,
                                                   const unsigned short* __restrict__ Wt,
                                                   unsigned short* __restrict__ Qb,
                                                   unsigned short* __restrict__ Kb,
                                                   unsigned short* __restrict__ Vtb) {
  __shared__ __align__(16) unsigned short As[2][128 * 64];  // 32 KB
  __shared__ __align__(16) unsigned short Bs[2][192 * 64];  // 48 KB
  const int tid = threadIdx.x;
  const int lane = tid & 63, w = tid >> 6;
  const int l15 = lane & 15, lg = lane >> 4;
  const int wm = w >> 1, wn = w & 1;

  // XCD-aware swizzle: 3072 blocks, 8 XCDs; 6 head-blocks of one m-tile land
  // on the same XCD, consecutive in dispatch -> x panel fetched once per m-tile.
  const int bid = blockIdx.x;
  const int xcd = bid & 7, pos = bid >> 3;   // pos in 0..383
  const int h = pos % 6;
  const int mt = xcd * 64 + pos / 6;
  const int m0 = mt * 128;
  const unsigned short* Wh = Wt + (size_t)h * 192 * ND;

  f32x4 acc[4][6];
#pragma unroll
  for (int i = 0; i < 4; i++)
#pragma unroll
    for (int j = 0; j < 6; j++) acc[i][j] = (f32x4){0.f, 0.f, 0.f, 0.f};

  // staging descriptors (chunk = 16 B; row has 8 chunks; source pre-swizzled)
  // A: 1024 chunks (j=0..3), B: 1536 chunks (j=0..5)
  int arow[4], acsw[4], brow[6], bcsw[6];
#pragma unroll
  for (int j = 0; j < 4; j++) {
    int chunk = j * 256 + tid;
    arow[j] = chunk >> 3;
    acsw[j] = (chunk & 7) ^ (arow[j] & 7);
  }
#pragma unroll
  for (int j = 0; j < 6; j++) {
    int chunk = j * 256 + tid;
    brow[j] = chunk >> 3;
    bcsw[j] = (chunk & 7) ^ (brow[j] & 7);
  }

#define STAGE(nb, k0)                                                              \
  do {                                                                             \
    _Pragma("unroll") for (int j = 0; j < 4; j++)                                  \
        gload16(&xb[(size_t)(m0 + arow[j]) * ND + (k0) + acsw[j] * 8],             \
                &As[nb][(j * 256 + w * 64) * 8]);                                  \
    _Pragma("unroll") for (int j = 0; j < 6; j++)                                  \
        gload16(&Wh[(size_t)brow[j] * ND + (k0) + bcsw[j] * 8],                    \
                &Bs[nb][(j * 256 + w * 64) * 8]);                                  \
  } while (0)

  STAGE(0, 0);
  __syncthreads();

  int cur = 0;
  for (int kt = 0; kt < 6; ++kt) {
    if (kt < 5) STAGE(cur ^ 1, (kt + 1) * 64);
    short8 af[4][2], bf[6][2];
#pragma unroll
    for (int mi = 0; mi < 4; mi++) {
      const int row = wm * 64 + mi * 16 + l15;
#pragma unroll
      for (int kk = 0; kk < 2; kk++)
        af[mi][kk] = *reinterpret_cast<const short8*>(
            &As[cur][row * 64 + (((kk * 4 + lg) ^ (row & 7)) * 8)]);
    }
#pragma unroll
    for (int ni = 0; ni < 6; ni++) {
      const int row = wn * 96 + ni * 16 + l15;
#pragma unroll
      for (int kk = 0; kk < 2; kk++)
        bf[ni][kk] = *reinterpret_cast<const short8*>(
            &Bs[cur][row * 64 + (((kk * 4 + lg) ^ (row & 7)) * 8)]);
    }
#pragma unroll
    for (int kk = 0; kk < 2; kk++)
#pragma unroll
      for (int mi = 0; mi < 4; mi++)
#pragma unroll
        for (int ni = 0; ni < 6; ni++)
          acc[mi][ni] = __builtin_amdgcn_mfma_f32_16x16x32_bf16(af[mi][kk], bf[ni][kk], acc[mi][ni], 0, 0, 0);
    __syncthreads();
    cur ^= 1;
  }

  // epilogue: D layout row=(lane>>4)*4+r (m side), col=lane&15 (n side)
  const int b = m0 >> 8, t0 = m0 & 255;
  const size_t bh = (size_t)b * NH + h;
#pragma unroll
  for (int mi = 0; mi < 4; mi++)
#pragma unroll
    for (int ni = 0; ni < 6; ni++) {
      const int col = wn * 96 + ni * 16 + l15;   // 0..191
      const int p = col >> 6, e = col & 63;
      const int mr = wm * 64 + mi * 16 + lg * 4;
      if (p == 2) {
        *reinterpret_cast<ushort4*>(&Vtb[(bh * 64 + e) * NT + t0 + mr]) = pack4(acc[mi][ni]);
      } else {
        unsigned short* dst = (p == 0) ? Qb : Kb;
        size_t base = (bh * NT + t0 + mr) * 64 + e;
#pragma unroll
        for (int r = 0; r < 4; r++) dst[base + (size_t)r * 64] = f2bf(acc[mi][ni][r]);
      }
    }
#undef STAGE
}

// ---------------- attention: one block per (b,h); 4 waves x 64 q-rows; kv tiles of 64
__global__ __launch_bounds__(256) void attn_fwd(const unsigned short* __restrict__ Qb,
                                                const unsigned short* __restrict__ Kb,
                                                const unsigned short* __restrict__ Vtb,
                                                unsigned short* __restrict__ AO) {
  __shared__ __align__(16) unsigned short Plds[4][64 * 64];
  const int bh = blockIdx.x;
  const int tid = threadIdx.x;
  const int w = tid >> 6, lane = tid & 63;
  const int l15 = lane & 15, lg = lane >> 4;
  const int q0 = w * 64;
  const unsigned short* Qh = Qb + (size_t)bh * NT * 64;
  const unsigned short* Kh = Kb + (size_t)bh * NT * 64;
  const unsigned short* Vh = Vtb + (size_t)bh * 64 * NT;
  unsigned short* P = Plds[w];
  const int swz = (l15 & 7) << 3;

  short8 qf[4][2];
#pragma unroll
  for (int mi = 0; mi < 4; mi++)
#pragma unroll
    for (int kb = 0; kb < 2; kb++)
      qf[mi][kb] = *reinterpret_cast<const short8*>(
          &Qh[(size_t)(q0 + mi * 16 + l15) * 64 + kb * 32 + lg * 8]);

  f32x4 ot[4][4];
#pragma unroll
  for (int i = 0; i < 4; i++)
#pragma unroll
    for (int j = 0; j < 4; j++) ot[i][j] = (f32x4){0.f, 0.f, 0.f, 0.f};
  float mprev[4], lsum[4];
#pragma unroll
  for (int mi = 0; mi < 4; mi++) { mprev[mi] = -1e30f; lsum[mi] = 0.f; }

  for (int tile = 0; tile <= w; ++tile) {
    const int kv0 = tile * 64;
    short8 kf[4][2];
#pragma unroll
    for (int ni = 0; ni < 4; ni++)
#pragma unroll
      for (int kb = 0; kb < 2; kb++)
        kf[ni][kb] = *reinterpret_cast<const short8*>(
            &Kh[(size_t)(kv0 + ni * 16 + l15) * 64 + kb * 32 + lg * 8]);

    f32x4 st[4][4];
#pragma unroll
    for (int i = 0; i < 4; i++)
#pragma unroll
      for (int j = 0; j < 4; j++) st[i][j] = (f32x4){0.f, 0.f, 0.f, 0.f};
#pragma unroll
    for (int ni = 0; ni < 4; ni++)
#pragma unroll
      for (int mi = 0; mi < 4; mi++)
#pragma unroll
        for (int kb = 0; kb < 2; kb++)
          st[ni][mi] = __builtin_amdgcn_mfma_f32_16x16x32_bf16(kf[ni][kb], qf[mi][kb], st[ni][mi], 0, 0, 0);

    if (tile == w) {
#pragma unroll
      for (int ni = 0; ni < 4; ni++)
#pragma unroll
        for (int mi = 0; mi < 4; mi++)
#pragma unroll
          for (int r = 0; r < 4; r++)
            if (kv0 + ni * 16 + lg * 4 + r > q0 + mi * 16 + l15) st[ni][mi][r] = -1e30f;
    }

#pragma unroll
    for (int mi = 0; mi < 4; mi++) {
      float mp = -1e30f;
#pragma unroll
      for (int ni = 0; ni < 4; ni++)
#pragma unroll
        for (int r = 0; r < 4; r++) mp = fmaxf(mp, st[ni][mi][r]);
      mp = fmaxf(mp, __shfl_xor(mp, 16));
      mp = fmaxf(mp, __shfl_xor(mp, 32));
      const float mnew = fmaxf(mprev[mi], mp);
      const float corr = __expf(mprev[mi] - mnew);
      mprev[mi] = mnew;
      float ls = 0.f;
#pragma unroll
      for (int ni = 0; ni < 4; ni++)
#pragma unroll
        for (int r = 0; r < 4; r++) {
          float pv = __expf(st[ni][mi][r] - mnew);
          st[ni][mi][r] = pv;
          ls += pv;
        }
      ls += __shfl_xor(ls, 16);
      ls += __shfl_xor(ls, 32);
      lsum[mi] = lsum[mi] * corr + ls;
#pragma unroll
      for (int erb = 0; erb < 4; erb++)
#pragma unroll
        for (int r = 0; r < 4; r++) ot[erb][mi][r] *= corr;
      const int qloc = mi * 16 + l15;
#pragma unroll
      for (int ni = 0; ni < 4; ni++)
        *reinterpret_cast<ushort4*>(&P[qloc * 64 + ((ni * 16 + lg * 4) ^ swz)]) = pack4(st[ni][mi]);
    }

    short8 va[4][2], pb[2][4];
#pragma unroll
    for (int erb = 0; erb < 4; erb++)
#pragma unroll
      for (int kk = 0; kk < 2; kk++)
        va[erb][kk] = *reinterpret_cast<const short8*>(
            &Vh[(size_t)(erb * 16 + l15) * NT + kv0 + kk * 32 + lg * 8]);
#pragma unroll
    for (int kk = 0; kk < 2; kk++)
#pragma unroll
      for (int mi = 0; mi < 4; mi++)
        pb[kk][mi] = *reinterpret_cast<const short8*>(
            &P[(mi * 16 + l15) * 64 + ((kk * 32 + lg * 8) ^ swz)]);
#pragma unroll
    for (int erb = 0; erb < 4; erb++)
#pragma unroll
      for (int mi = 0; mi < 4; mi++)
#pragma unroll
        for (int kk = 0; kk < 2; kk++)
          ot[erb][mi] = __builtin_amdgcn_mfma_f32_16x16x32_bf16(va[erb][kk], pb[kk][mi], ot[erb][mi], 0, 0, 0);
  }

  const int b = bh / NH, h = bh % NH;
#pragma unroll
  for (int mi = 0; mi < 4; mi++) {
    const float rl = 1.0f / lsum[mi];
    const int q = q0 + mi * 16 + l15;
#pragma unroll
    for (int erb = 0; erb < 4; erb++) {
      f32x4 v;
#pragma unroll
      for (int r = 0; r < 4; r++) v[r] = ot[erb][mi][r] * rl;
      *reinterpret_cast<ushort4*>(&AO[((size_t)(b * NT + q)) * ND + h * 64 + erb * 16 + lg * 4]) =
          pack4(v);
    }
  }
}

// ---------------- output projection: out[m][n] = AO[m][k] * W_out[k][n] + b_out[n]
__global__ __launch_bounds__(256) void out_gemm(const unsigned short* __restrict__ AO,
                                                const unsigned short* __restrict__ Wot,
                                                const float* __restrict__ bout,
                                                float* __restrict__ out) {
  __shared__ __align__(16) unsigned short As[128 * 48];
  __shared__ __align__(16) unsigned short Bs[64 * 48];
  const int tid = threadIdx.x;
  const int lane = tid & 63, w = tid >> 6;
  const int l15 = lane & 15, lg = lane >> 4;
  const int wm = w >> 1, wn = w & 1;
  const int n0 = blockIdx.x * 64;
  const int m0 = blockIdx.y * 128;

  f32x4 acc[4][2];
#pragma unroll
  for (int i = 0; i < 4; i++)
#pragma unroll
    for (int j = 0; j < 2; j++) acc[i][j] = (f32x4){0.f, 0.f, 0.f, 0.f};

  const int arow = tid >> 2, ak = (tid & 3) * 8;

  for (int kt = 0; kt < 12; ++kt) {
    const int k0 = kt * 32;
    short8 av0 = *reinterpret_cast<const short8*>(&AO[(size_t)(m0 + arow) * ND + k0 + ak]);
    short8 av1 = *reinterpret_cast<const short8*>(&AO[(size_t)(m0 + 64 + arow) * ND + k0 + ak]);
    short8 bv = *reinterpret_cast<const short8*>(&Wot[(size_t)(n0 + arow) * ND + k0 + ak]);
    __syncthreads();
    *reinterpret_cast<short8*>(&As[arow * 48 + ak]) = av0;
    *reinterpret_cast<short8*>(&As[(64 + arow) * 48 + ak]) = av1;
    *reinterpret_cast<short8*>(&Bs[arow * 48 + ak]) = bv;
    __syncthreads();
    short8 af[4], bf[2];
#pragma unroll
    for (int mi = 0; mi < 4; mi++)
      af[mi] = *reinterpret_cast<const short8*>(&As[(wm * 64 + mi * 16 + l15) * 48 + lg * 8]);
#pragma unroll
    for (int ni = 0; ni < 2; ni++)
      bf[ni] = *reinterpret_cast<const short8*>(&Bs[(wn * 32 + ni * 16 + l15) * 48 + lg * 8]);
#pragma unroll
    for (int mi = 0; mi < 4; mi++)
#pragma unroll
      for (int ni = 0; ni < 2; ni++)
        acc[mi][ni] = __builtin_amdgcn_mfma_f32_16x16x32_bf16(af[mi], bf[ni], acc[mi][ni], 0, 0, 0);
  }

#pragma unroll
  for (int mi = 0; mi < 4; mi++)
#pragma unroll
    for (int ni = 0; ni < 2; ni++) {
      const int c = n0 + wn * 32 + ni * 16 + l15;
      const int mr = m0 + wm * 64 + mi * 16 + lg * 4;
      const float bb = bout[c];
#pragma unroll
      for (int r = 0; r < 4; r++) out[(size_t)(mr + r) * ND + c] = acc[mi][ni][r] + bb;
    }
}

// ---------------- launcher
extern "C" void kernel_launch(void* const* d_in, const int* in_sizes, int n_in,
                              void* d_out, int out_size, void* d_ws, size_t ws_size,
                              hipStream_t stream) {
  const float* x = (const float*)d_in[0];
  const float* Wqkv = (const float*)d_in[1];
  const float* Wout = (const float*)d_in[2];
  const float* bout = (const float*)d_in[3];

  char* ws = (char*)d_ws;
  const size_t SZ = (size_t)NBATCH * NH * NT * NHS * 2;  // 50331648
  unsigned short* Qb  = (unsigned short*)(ws);
  unsigned short* Kb  = (unsigned short*)(ws + SZ);
  unsigned short* Vtb = (unsigned short*)(ws + 2 * SZ);
  unsigned short* AO  = (unsigned short*)(ws + 3 * SZ);
  // xb aliases AO: xb's lifetime (x_to_bf16 .. qkv_gemm) ends before attn_fwd
  // writes AO; strict stream ordering makes this safe and saves 50 MB of ws.
  unsigned short* xb  = AO;
  unsigned short* Wqt = (unsigned short*)(ws + 4 * SZ);            // 884736 B
  unsigned short* Wot = (unsigned short*)(ws + 4 * SZ + 884736);   // 294912 B

  x_to_bf16<<<12288, 256, 0, stream>>>(x, xb);
  prep_wqkv<<<1728, 256, 0, stream>>>(Wqkv, Wqt);
  prep_wout<<<576, 256, 0, stream>>>(Wout, Wot);
  qkv_gemm<<<3072, 256, 0, stream>>>(xb, Wqt, Qb, Kb, Vtb);
  attn_fwd<<<NBATCH * NH, 256, 0, stream>>>(Qb, Kb, Vtb, AO);
  out_gemm<<<dim3(6, 512), 256, 0, stream>>>(AO, Wot, bout, (float*)d_out);
}

// Round 3
// 251.615 us; speedup vs baseline: 1.3912x; 1.0487x over previous
//
#include <hip/hip_runtime.h>

// Multi-head causal attention: B=256 T=256 D=384 H=6 HS=64
// Pipeline: x->bf16 | W preps | per-head fused QKV GEMM (128x192 tile,
// global_load_lds + XOR swizzle + XCD swizzle, 2-phase prefetch)
// -> flash attention (1-wave jobs, S^T trick, exp2-domain, defer-max)
// -> out GEMM + bias.

typedef __attribute__((ext_vector_type(8))) short short8;
typedef __attribute__((ext_vector_type(4))) float f32x4;

#define NBATCH 256
#define NT 256
#define ND 384
#define NH 6
#define NHS 64

__device__ __forceinline__ unsigned short f2bf(float f) {
  unsigned int u = __float_as_uint(f);
  u += 0x7fffu + ((u >> 16) & 1u);
  return (unsigned short)(u >> 16);
}

__device__ __forceinline__ ushort4 pack4(f32x4 v) {
  ushort4 p;
  p.x = f2bf(v[0]); p.y = f2bf(v[1]); p.z = f2bf(v[2]); p.w = f2bf(v[3]);
  return p;
}

__device__ __forceinline__ unsigned int cvtpk(float lo, float hi) {
  unsigned int r;
  asm("v_cvt_pk_bf16_f32 %0, %1, %2" : "=v"(r) : "v"(lo), "v"(hi));
  return r;
}

__device__ __forceinline__ void gload16(const void* g, void* l) {
  __builtin_amdgcn_global_load_lds(
      (const __attribute__((address_space(1))) void*)g,
      (__attribute__((address_space(3))) void*)l, 16, 0, 0);
}

// ---------------- x [B*T][D] f32 -> bf16
__global__ __launch_bounds__(256) void x_to_bf16(const float* __restrict__ x,
                                                 unsigned short* __restrict__ xb) {
  size_t i = ((size_t)blockIdx.x * 256 + threadIdx.x) * 8;  // 25165824 total
  float4 a = *reinterpret_cast<const float4*>(&x[i]);
  float4 b = *reinterpret_cast<const float4*>(&x[i + 4]);
  ushort4 lo, hi;
  lo.x = f2bf(a.x); lo.y = f2bf(a.y); lo.z = f2bf(a.z); lo.w = f2bf(a.w);
  hi.x = f2bf(b.x); hi.y = f2bf(b.y); hi.z = f2bf(b.z); hi.w = f2bf(b.w);
  *reinterpret_cast<ushort4*>(&xb[i]) = lo;
  *reinterpret_cast<ushort4*>(&xb[i + 4]) = hi;
}

// ---------------- prep: W_qkv [H][D][192] f32 -> Wt [H][192][D] bf16
// Q rows scaled by 0.125 * log2(e): softmax then runs in exp2 domain.
__global__ __launch_bounds__(256) void prep_wqkv(const float* __restrict__ W,
                                                 unsigned short* __restrict__ Wt) {
  int idx = blockIdx.x * 256 + threadIdx.x;        // NH*192*ND = 442368
  int h = idx / (192 * ND);
  int rem = idx % (192 * ND);
  int e = rem / ND;
  int d = rem % ND;
  float v = W[((size_t)h * ND + d) * 192 + e];
  if (e < 64) v *= 0.125f * 1.44269504088896340736f;
  Wt[idx] = f2bf(v);
}

// ---------------- prep: W_out [384][384] f32 -> Wot [n][k] bf16 (transposed)
__global__ __launch_bounds__(256) void prep_wout(const float* __restrict__ W,
                                                 unsigned short* __restrict__ Wt) {
  int idx = blockIdx.x * 256 + threadIdx.x;        // 147456
  int n = idx / ND;
  int k = idx % ND;
  Wt[idx] = f2bf(W[(size_t)k * ND + n]);
}

// ---------------- fused per-head QKV GEMM: C[128 m][192 n] per block
__global__ __launch_bounds__(256, 2) void qkv_gemm(const unsigned short* __restrict__ xb,
                                                   const unsigned short* __restrict__ Wt,
                                                   unsigned short* __restrict__ Qb,
                                                   unsigned short* __restrict__ Kb,
                                                   unsigned short* __restrict__ Vtb) {
  __shared__ __align__(16) unsigned short As[2][128 * 64];  // 32 KB
  __shared__ __align__(16) unsigned short Bs[2][192 * 64];  // 48 KB
  const int tid = threadIdx.x;
  const int lane = tid & 63, w = tid >> 6;
  const int l15 = lane & 15, lg = lane >> 4;
  const int wm = w >> 1, wn = w & 1;

  const int bid = blockIdx.x;
  const int xcd = bid & 7, pos = bid >> 3;   // pos in 0..383
  const int h = pos % 6;
  const int mt = xcd * 64 + pos / 6;
  const int m0 = mt * 128;
  const unsigned short* Wh = Wt + (size_t)h * 192 * ND;

  f32x4 acc[4][6];
#pragma unroll
  for (int i = 0; i < 4; i++)
#pragma unroll
    for (int j = 0; j < 6; j++) acc[i][j] = (f32x4){0.f, 0.f, 0.f, 0.f};

  int arow[4], acsw[4], brow[6], bcsw[6];
#pragma unroll
  for (int j = 0; j < 4; j++) {
    int chunk = j * 256 + tid;
    arow[j] = chunk >> 3;
    acsw[j] = (chunk & 7) ^ (arow[j] & 7);
  }
#pragma unroll
  for (int j = 0; j < 6; j++) {
    int chunk = j * 256 + tid;
    brow[j] = chunk >> 3;
    bcsw[j] = (chunk & 7) ^ (brow[j] & 7);
  }

#define STAGE(nb, k0)                                                              \
  do {                                                                             \
    _Pragma("unroll") for (int j = 0; j < 4; j++)                                  \
        gload16(&xb[(size_t)(m0 + arow[j]) * ND + (k0) + acsw[j] * 8],             \
                &As[nb][(j * 256 + w * 64) * 8]);                                  \
    _Pragma("unroll") for (int j = 0; j < 6; j++)                                  \
        gload16(&Wh[(size_t)brow[j] * ND + (k0) + bcsw[j] * 8],                    \
                &Bs[nb][(j * 256 + w * 64) * 8]);                                  \
  } while (0)

  STAGE(0, 0);
  __syncthreads();

  int cur = 0;
  for (int kt = 0; kt < 6; ++kt) {
    if (kt < 5) STAGE(cur ^ 1, (kt + 1) * 64);
    short8 af[4][2], bf[6][2];
#pragma unroll
    for (int mi = 0; mi < 4; mi++) {
      const int row = wm * 64 + mi * 16 + l15;
#pragma unroll
      for (int kk = 0; kk < 2; kk++)
        af[mi][kk] = *reinterpret_cast<const short8*>(
            &As[cur][row * 64 + (((kk * 4 + lg) ^ (row & 7)) * 8)]);
    }
#pragma unroll
    for (int ni = 0; ni < 6; ni++) {
      const int row = wn * 96 + ni * 16 + l15;
#pragma unroll
      for (int kk = 0; kk < 2; kk++)
        bf[ni][kk] = *reinterpret_cast<const short8*>(
            &Bs[cur][row * 64 + (((kk * 4 + lg) ^ (row & 7)) * 8)]);
    }
#pragma unroll
    for (int kk = 0; kk < 2; kk++)
#pragma unroll
      for (int mi = 0; mi < 4; mi++)
#pragma unroll
        for (int ni = 0; ni < 6; ni++)
          acc[mi][ni] = __builtin_amdgcn_mfma_f32_16x16x32_bf16(af[mi][kk], bf[ni][kk], acc[mi][ni], 0, 0, 0);
    __syncthreads();
    cur ^= 1;
  }

  const int b = m0 >> 8, t0 = m0 & 255;
  const size_t bh = (size_t)b * NH + h;
#pragma unroll
  for (int mi = 0; mi < 4; mi++)
#pragma unroll
    for (int ni = 0; ni < 6; ni++) {
      const int col = wn * 96 + ni * 16 + l15;   // 0..191
      const int p = col >> 6, e = col & 63;
      const int mr = wm * 64 + mi * 16 + lg * 4;
      if (p == 2) {
        *reinterpret_cast<ushort4*>(&Vtb[(bh * 64 + e) * NT + t0 + mr]) = pack4(acc[mi][ni]);
      } else {
        unsigned short* dst = (p == 0) ? Qb : Kb;
        size_t base = (bh * NT + t0 + mr) * 64 + e;
#pragma unroll
        for (int r = 0; r < 4; r++) dst[base + (size_t)r * 64] = f2bf(acc[mi][ni][r]);
      }
    }
#undef STAGE
}

// ---------------- attention: 1 wave per block; job = (bh, 32-row q-tile).
// 12288 jobs, independent retirement (no imbalance). S^T trick (mfma(K,Q)),
// exp2-domain softmax (log2e folded into Q), defer-max rescale (THR=8),
// cvt_pk P-packing, 4 KB wave-private XOR-swizzled P buffer.
__global__ __launch_bounds__(64, 4) void attn_fwd(const unsigned short* __restrict__ Qb,
                                                  const unsigned short* __restrict__ Kb,
                                                  const unsigned short* __restrict__ Vtb,
                                                  unsigned short* __restrict__ AO) {
  __shared__ __align__(16) unsigned short P[32 * 64];  // 4 KB
  const int bid = blockIdx.x;
  // XCD swizzle: 8 q-jobs of each bh co-locate on one XCD (K/V L2-resident)
  const int xcd = bid & 7, pos = bid >> 3;     // pos 0..1535
  const int bh = xcd * 192 + (pos >> 3);
  const int qt = pos & 7;
  const int lane = threadIdx.x;
  const int l15 = lane & 15, lg = lane >> 4;
  const int q0 = qt * 32;
  const unsigned short* Qh = Qb + (size_t)bh * NT * 64;
  const unsigned short* Kh = Kb + (size_t)bh * NT * 64;
  const unsigned short* Vh = Vtb + (size_t)bh * 64 * NT;
  const int swz = (l15 & 7) << 3;

  short8 qf[2][2];
#pragma unroll
  for (int mi = 0; mi < 2; mi++)
#pragma unroll
    for (int kb = 0; kb < 2; kb++)
      qf[mi][kb] = *reinterpret_cast<const short8*>(
          &Qh[(size_t)(q0 + mi * 16 + l15) * 64 + kb * 32 + lg * 8]);

  f32x4 ot[4][2];  // O^T: [e-block][q-block]
#pragma unroll
  for (int i = 0; i < 4; i++)
#pragma unroll
    for (int j = 0; j < 2; j++) ot[i][j] = (f32x4){0.f, 0.f, 0.f, 0.f};
  float mrun[2] = {-3e38f, -3e38f}, lsum[2] = {0.f, 0.f};

  const int ntiles = (qt >> 1) + 1;
  for (int tile = 0; tile < ntiles; ++tile) {
    const int kv0 = tile * 64;
    f32x4 st[4][2];
#pragma unroll
    for (int i = 0; i < 4; i++)
#pragma unroll
      for (int j = 0; j < 2; j++) st[i][j] = (f32x4){0.f, 0.f, 0.f, 0.f};
#pragma unroll
    for (int ni = 0; ni < 4; ni++) {
      const short8 kf0 = *reinterpret_cast<const short8*>(
          &Kh[(size_t)(kv0 + ni * 16 + l15) * 64 + lg * 8]);
      const short8 kf1 = *reinterpret_cast<const short8*>(
          &Kh[(size_t)(kv0 + ni * 16 + l15) * 64 + 32 + lg * 8]);
#pragma unroll
      for (int mi = 0; mi < 2; mi++) {
        st[ni][mi] = __builtin_amdgcn_mfma_f32_16x16x32_bf16(kf0, qf[mi][0], st[ni][mi], 0, 0, 0);
        st[ni][mi] = __builtin_amdgcn_mfma_f32_16x16x32_bf16(kf1, qf[mi][1], st[ni][mi], 0, 0, 0);
      }
    }

    if (tile == ntiles - 1) {  // causal mask (last tile always touches diagonal)
#pragma unroll
      for (int ni = 0; ni < 4; ni++)
#pragma unroll
        for (int mi = 0; mi < 2; mi++)
#pragma unroll
          for (int r = 0; r < 4; r++)
            if (kv0 + ni * 16 + lg * 4 + r > q0 + mi * 16 + l15) st[ni][mi][r] = -1e30f;
    }

#pragma unroll
    for (int mi = 0; mi < 2; mi++) {
      float tmax = st[0][mi][0];
#pragma unroll
      for (int ni = 0; ni < 4; ni++)
#pragma unroll
        for (int r = 0; r < 4; r++) tmax = fmaxf(tmax, st[ni][mi][r]);
      tmax = fmaxf(tmax, __shfl_xor(tmax, 16));
      tmax = fmaxf(tmax, __shfl_xor(tmax, 32));
      if (__any(tmax > mrun[mi] + 8.0f)) {   // defer-max: rescale only when needed
        const float mnew = fmaxf(mrun[mi], tmax);
        const float corr = __builtin_amdgcn_exp2f(mrun[mi] - mnew);
        lsum[mi] *= corr;
#pragma unroll
        for (int erb = 0; erb < 4; erb++)
#pragma unroll
          for (int r = 0; r < 4; r++) ot[erb][mi][r] *= corr;
        mrun[mi] = mnew;
      }
      const float mref = mrun[mi];
      float ls = 0.f;
      const int prow = (mi * 16 + l15) * 64;
#pragma unroll
      for (int ni = 0; ni < 4; ni++) {
        const float p0 = __builtin_amdgcn_exp2f(st[ni][mi][0] - mref);
        const float p1 = __builtin_amdgcn_exp2f(st[ni][mi][1] - mref);
        const float p2 = __builtin_amdgcn_exp2f(st[ni][mi][2] - mref);
        const float p3 = __builtin_amdgcn_exp2f(st[ni][mi][3] - mref);
        ls += (p0 + p1) + (p2 + p3);
        uint2 wv;
        wv.x = cvtpk(p0, p1);
        wv.y = cvtpk(p2, p3);
        *reinterpret_cast<uint2*>(&P[prow + ((ni * 16 + lg * 4) ^ swz)]) = wv;
      }
      ls += __shfl_xor(ls, 16);
      ls += __shfl_xor(ls, 32);
      lsum[mi] += ls;
    }

    // PV: O^T[e][q] += V^T[e][kv] * P^T[kv][q]
    short8 pb[2][2];
#pragma unroll
    for (int kk = 0; kk < 2; kk++)
#pragma unroll
      for (int mi = 0; mi < 2; mi++)
        pb[kk][mi] = *reinterpret_cast<const short8*>(
            &P[(mi * 16 + l15) * 64 + ((kk * 32 + lg * 8) ^ swz)]);
#pragma unroll
    for (int erb = 0; erb < 4; erb++) {
      const short8 va0 = *reinterpret_cast<const short8*>(
          &Vh[(size_t)(erb * 16 + l15) * NT + kv0 + lg * 8]);
      const short8 va1 = *reinterpret_cast<const short8*>(
          &Vh[(size_t)(erb * 16 + l15) * NT + kv0 + 32 + lg * 8]);
#pragma unroll
      for (int mi = 0; mi < 2; mi++) {
        ot[erb][mi] = __builtin_amdgcn_mfma_f32_16x16x32_bf16(va0, pb[0][mi], ot[erb][mi], 0, 0, 0);
        ot[erb][mi] = __builtin_amdgcn_mfma_f32_16x16x32_bf16(va1, pb[1][mi], ot[erb][mi], 0, 0, 0);
      }
    }
  }

  const int b = bh / NH, h = bh % NH;
#pragma unroll
  for (int mi = 0; mi < 2; mi++) {
    const float rl = 1.0f / lsum[mi];
    const int q = q0 + mi * 16 + l15;
#pragma unroll
    for (int erb = 0; erb < 4; erb++) {
      f32x4 v;
#pragma unroll
      for (int r = 0; r < 4; r++) v[r] = ot[erb][mi][r] * rl;
      *reinterpret_cast<ushort4*>(&AO[((size_t)(b * NT + q)) * ND + h * 64 + erb * 16 + lg * 4]) =
          pack4(v);
    }
  }
}

// ---------------- output projection: out[m][n] = AO[m][k] * W_out[k][n] + b_out[n]
__global__ __launch_bounds__(256) void out_gemm(const unsigned short* __restrict__ AO,
                                                const unsigned short* __restrict__ Wot,
                                                const float* __restrict__ bout,
                                                float* __restrict__ out) {
  __shared__ __align__(16) unsigned short As[128 * 48];
  __shared__ __align__(16) unsigned short Bs[64 * 48];
  const int tid = threadIdx.x;
  const int lane = tid & 63, w = tid >> 6;
  const int l15 = lane & 15, lg = lane >> 4;
  const int wm = w >> 1, wn = w & 1;
  const int n0 = blockIdx.x * 64;
  const int m0 = blockIdx.y * 128;

  f32x4 acc[4][2];
#pragma unroll
  for (int i = 0; i < 4; i++)
#pragma unroll
    for (int j = 0; j < 2; j++) acc[i][j] = (f32x4){0.f, 0.f, 0.f, 0.f};

  const int arow = tid >> 2, ak = (tid & 3) * 8;

  for (int kt = 0; kt < 12; ++kt) {
    const int k0 = kt * 32;
    short8 av0 = *reinterpret_cast<const short8*>(&AO[(size_t)(m0 + arow) * ND + k0 + ak]);
    short8 av1 = *reinterpret_cast<const short8*>(&AO[(size_t)(m0 + 64 + arow) * ND + k0 + ak]);
    short8 bv = *reinterpret_cast<const short8*>(&Wot[(size_t)(n0 + arow) * ND + k0 + ak]);
    __syncthreads();
    *reinterpret_cast<short8*>(&As[arow * 48 + ak]) = av0;
    *reinterpret_cast<short8*>(&As[(64 + arow) * 48 + ak]) = av1;
    *reinterpret_cast<short8*>(&Bs[arow * 48 + ak]) = bv;
    __syncthreads();
    short8 af[4], bf[2];
#pragma unroll
    for (int mi = 0; mi < 4; mi++)
      af[mi] = *reinterpret_cast<const short8*>(&As[(wm * 64 + mi * 16 + l15) * 48 + lg * 8]);
#pragma unroll
    for (int ni = 0; ni < 2; ni++)
      bf[ni] = *reinterpret_cast<const short8*>(&Bs[(wn * 32 + ni * 16 + l15) * 48 + lg * 8]);
#pragma unroll
    for (int mi = 0; mi < 4; mi++)
#pragma unroll
      for (int ni = 0; ni < 2; ni++)
        acc[mi][ni] = __builtin_amdgcn_mfma_f32_16x16x32_bf16(af[mi], bf[ni], acc[mi][ni], 0, 0, 0);
  }

#pragma unroll
  for (int mi = 0; mi < 4; mi++)
#pragma unroll
    for (int ni = 0; ni < 2; ni++) {
      const int c = n0 + wn * 32 + ni * 16 + l15;
      const int mr = m0 + wm * 64 + mi * 16 + lg * 4;
      const float bb = bout[c];
#pragma unroll
      for (int r = 0; r < 4; r++) out[(size_t)(mr + r) * ND + c] = acc[mi][ni][r] + bb;
    }
}

// ---------------- launcher
extern "C" void kernel_launch(void* const* d_in, const int* in_sizes, int n_in,
                              void* d_out, int out_size, void* d_ws, size_t ws_size,
                              hipStream_t stream) {
  const float* x = (const float*)d_in[0];
  const float* Wqkv = (const float*)d_in[1];
  const float* Wout = (const float*)d_in[2];
  const float* bout = (const float*)d_in[3];

  char* ws = (char*)d_ws;
  const size_t SZ = (size_t)NBATCH * NH * NT * NHS * 2;  // 50331648
  unsigned short* Qb  = (unsigned short*)(ws);
  unsigned short* Kb  = (unsigned short*)(ws + SZ);
  unsigned short* Vtb = (unsigned short*)(ws + 2 * SZ);
  unsigned short* AO  = (unsigned short*)(ws + 3 * SZ);
  // xb aliases AO: xb's lifetime (x_to_bf16 .. qkv_gemm) ends before attn_fwd
  // writes AO; strict stream ordering makes this safe.
  unsigned short* xb  = AO;
  unsigned short* Wqt = (unsigned short*)(ws + 4 * SZ);            // 884736 B
  unsigned short* Wot = (unsigned short*)(ws + 4 * SZ + 884736);   // 294912 B

  x_to_bf16<<<12288, 256, 0, stream>>>(x, xb);
  prep_wqkv<<<1728, 256, 0, stream>>>(Wqkv, Wqt);
  prep_wout<<<576, 256, 0, stream>>>(Wout, Wot);
  qkv_gemm<<<3072, 256, 0, stream>>>(xb, Wqt, Qb, Kb, Vtb);
  attn_fwd<<<12288, 64, 0, stream>>>(Qb, Kb, Vtb, AO);
  out_gemm<<<dim3(6, 512), 256, 0, stream>>>(AO, Wot, bout, (float*)d_out);
}